// Round 1
// baseline (1741.197 us; speedup 1.0000x reference)
//
#include <hip/hip_runtime.h>
#include <math.h>

#define Bb 8
#define Ll 1024
#define Dd 256
#define Ee 8
#define Hh 1024
#define LMAXc 512
#define NTOK (Bb*Dd)   // 2048

#define BM 64
#define BN 64
#define BKK 32

__device__ __forceinline__ float gelu_f(float x) {
    return 0.5f * x * (1.0f + erff(x * 0.70710678118654752440f));
}

// -------- repack conv weights [3][D][D][3] -> [layer][k][o][i] --------
__global__ __launch_bounds__(256) void repack_conv_w(const float* __restrict__ cw,
                                                     float* __restrict__ wr) {
    int idx = blockIdx.x * 256 + threadIdx.x;      // 3*3*256*256 = 589824 exact
    int i = idx & (Dd - 1);
    int o = (idx >> 8) & (Dd - 1);
    int lk = idx >> 16;                            // layer*3 + k
    int layer = lk / 3;
    int k = lk % 3;
    wr[idx] = cw[(((size_t)layer * Dd + o) * Dd + i) * 3 + k];
}

// -------- dilated causal-'same' conv as 3 shifted NT-GEMMs + GELU --------
__global__ __launch_bounds__(256) void conv_gemm(const float* __restrict__ in,   // [B][L][D]
                                                 const float* __restrict__ wrL,  // [3][D][D] (k,o,i)
                                                 const float* __restrict__ bias, // [D]
                                                 float* __restrict__ out,        // [B][L][D]
                                                 int dil) {
    __shared__ float As[BKK][BM + 4];
    __shared__ float Bs[BKK][BN + 4];
    int t = threadIdx.x;
    int tx = t & 15, ty = t >> 4;
    int row0 = blockIdx.x * BM;            // over B*L
    int b = row0 / Ll;
    int l0 = row0 % Ll;
    int col0 = blockIdx.y * BN;            // out channel
    float acc[4][4] = {};
    for (int k = 0; k < 3; ++k) {
        int sh = (k - 1) * dil;
        const float* wk = wrL + (size_t)k * Dd * Dd;
        for (int kb = 0; kb < Dd; kb += BKK) {
            #pragma unroll
            for (int i = 0; i < 8; ++i) {
                int idx = t + i * 256;
                int kk = idx & 31, m = idx >> 5;
                int l = l0 + m + sh;
                As[kk][m] = (l >= 0 && l < Ll) ? in[((size_t)b * Ll + l) * Dd + kb + kk] : 0.0f;
            }
            #pragma unroll
            for (int i = 0; i < 8; ++i) {
                int idx = t + i * 256;
                int kk = idx & 31, n = idx >> 5;
                Bs[kk][n] = wk[(size_t)(col0 + n) * Dd + kb + kk];
            }
            __syncthreads();
            #pragma unroll
            for (int kk = 0; kk < BKK; ++kk) {
                float a[4], bv[4];
                #pragma unroll
                for (int j = 0; j < 4; ++j) a[j] = As[kk][ty * 4 + j];
                #pragma unroll
                for (int j = 0; j < 4; ++j) bv[j] = Bs[kk][tx * 4 + j];
                #pragma unroll
                for (int i = 0; i < 4; ++i)
                    #pragma unroll
                    for (int j = 0; j < 4; ++j) acc[i][j] += a[i] * bv[j];
            }
            __syncthreads();
        }
    }
    #pragma unroll
    for (int i = 0; i < 4; ++i) {
        int l = l0 + ty * 4 + i;
        #pragma unroll
        for (int j = 0; j < 4; ++j) {
            int o = col0 + tx * 4 + j;
            out[((size_t)b * Ll + l) * Dd + o] = gelu_f(acc[i][j] + bias[o]);
        }
    }
}

// -------- logits accumulate: logits[t][e] += sum_l h[b][l][d]*fl_w[e][l] --------
__global__ __launch_bounds__(256) void logits_accum(const float* __restrict__ h,    // [B][L][D]
                                                    const float* __restrict__ fl_w, // [E][L]
                                                    float* __restrict__ logits) {   // [NTOK][E] zeroed
    int b = blockIdx.x;
    int chunk = blockIdx.y;  // 8 chunks of 128
    __shared__ float wsm[Ee][128];
    for (int i = threadIdx.x; i < Ee * 128; i += 256) {
        int e = i >> 7, l = i & 127;
        wsm[e][l] = fl_w[e * Ll + chunk * 128 + l];
    }
    __syncthreads();
    int d = threadIdx.x;
    float acc[Ee] = {};
    for (int l = 0; l < 128; ++l) {
        float v = h[((size_t)b * Ll + chunk * 128 + l) * Dd + d];
        #pragma unroll
        for (int e = 0; e < Ee; ++e) acc[e] += v * wsm[e][l];
    }
    int tok = b * Dd + d;
    #pragma unroll
    for (int e = 0; e < Ee; ++e) atomicAdd(&logits[tok * Ee + e], acc[e]);
}

// -------- sigmoid -> softmax -> top2 (stable, lower-index ties) -> gates --------
__global__ __launch_bounds__(256) void gates_final(const float* __restrict__ logits,
                                                   const float* __restrict__ fl_b,
                                                   float* __restrict__ gates) {
    int tok = blockIdx.x * 256 + threadIdx.x;
    if (tok >= NTOK) return;
    float s[Ee];
    #pragma unroll
    for (int e = 0; e < Ee; ++e) {
        float z = logits[tok * Ee + e] + fl_b[e];
        s[e] = 1.0f / (1.0f + expf(-z));
    }
    float mx = s[0];
    #pragma unroll
    for (int e = 1; e < Ee; ++e) mx = fmaxf(mx, s[e]);
    float p[Ee];
    #pragma unroll
    for (int e = 0; e < Ee; ++e) p[e] = expf(s[e] - mx);
    int i1 = 0;
    #pragma unroll
    for (int e = 1; e < Ee; ++e) if (p[e] > p[i1]) i1 = e;
    int i2 = (i1 == 0) ? 1 : 0;
    #pragma unroll
    for (int e = 0; e < Ee; ++e) {
        if (e == i1 || e == i2) continue;
        if (p[e] > p[i2]) i2 = e;
    }
    float inv = 1.0f / (p[i1] + p[i2]);
    #pragma unroll
    for (int e = 0; e < Ee; ++e) gates[tok * Ee + e] = 0.0f;
    gates[tok * Ee + i1] = p[i1] * inv;
    gates[tok * Ee + i2] = p[i2] * inv;
}

// -------- per-expert avg-pool downsample, zero-padded to LMAX --------
__global__ __launch_bounds__(256) void downsample(const float* __restrict__ x, // [B][L][D]
                                                  float* __restrict__ xe) {    // [E][NTOK][LMAX]
    int e = blockIdx.y;
    int tok = blockIdx.x;
    int b = tok >> 8, d = tok & 255;
    int f = e + 2;
    int Li = Ll / f;
    float invf = 1.0f / (float)f;
    for (int j = threadIdx.x; j < LMAXc; j += 256) {
        float v = 0.0f;
        if (j < Li) {
            for (int r = 0; r < f; ++r) v += x[((size_t)b * Ll + j * f + r) * Dd + d];
            v *= invf;
        }
        xe[((size_t)e * NTOK + tok) * LMAXc + j] = v;
    }
}

// -------- generic per-expert NT-GEMM: C = act(A @ B^T + bias) --------
__global__ __launch_bounds__(256) void gemm_nt(const float* __restrict__ Ag,  // [E][M][K]
                                               const float* __restrict__ Bg,  // [E][N][K]
                                               const float* __restrict__ biasg,// [E][N]
                                               float* __restrict__ Cg,        // [E][M][N]
                                               int M, int N, int Kd, int do_gelu) {
    int e = blockIdx.z;
    const float* A = Ag + (size_t)e * M * Kd;
    const float* Bw = Bg + (size_t)e * N * Kd;
    const float* bias = biasg + (size_t)e * N;
    float* C = Cg + (size_t)e * M * N;

    __shared__ float As[BKK][BM + 4];
    __shared__ float Bs[BKK][BN + 4];
    int t = threadIdx.x;
    int tx = t & 15, ty = t >> 4;
    int row0 = blockIdx.x * BM;
    int col0 = blockIdx.y * BN;
    float acc[4][4] = {};
    for (int kb = 0; kb < Kd; kb += BKK) {
        #pragma unroll
        for (int i = 0; i < 8; ++i) {
            int idx = t + i * 256;
            int kk = idx & 31, m = idx >> 5;
            As[kk][m] = A[(size_t)(row0 + m) * Kd + kb + kk];
        }
        #pragma unroll
        for (int i = 0; i < 8; ++i) {
            int idx = t + i * 256;
            int kk = idx & 31, n = idx >> 5;
            Bs[kk][n] = Bw[(size_t)(col0 + n) * Kd + kb + kk];
        }
        __syncthreads();
        #pragma unroll
        for (int kk = 0; kk < BKK; ++kk) {
            float a[4], bv[4];
            #pragma unroll
            for (int j = 0; j < 4; ++j) a[j] = As[kk][ty * 4 + j];
            #pragma unroll
            for (int j = 0; j < 4; ++j) bv[j] = Bs[kk][tx * 4 + j];
            #pragma unroll
            for (int i = 0; i < 4; ++i)
                #pragma unroll
                for (int j = 0; j < 4; ++j) acc[i][j] += a[i] * bv[j];
        }
        __syncthreads();
    }
    #pragma unroll
    for (int i = 0; i < 4; ++i) {
        int r = row0 + ty * 4 + i;
        #pragma unroll
        for (int j = 0; j < 4; ++j) {
            int c = col0 + tx * 4 + j;
            float v = acc[i][j] + bias[c];
            if (do_gelu) v = gelu_f(v);
            C[(size_t)r * N + c] = v;
        }
    }
}

// -------- GEMM3 fused with gate-combine + b3: outacc[t][o] = sum_e g[t][e]*(h2_e@w3_e^T + b3_e) --------
__global__ __launch_bounds__(256) void gemm3_combine(const float* __restrict__ h2,   // [E][NTOK][H]
                                                     const float* __restrict__ w3,   // [E][H][H]
                                                     const float* __restrict__ b3,   // [E][H]
                                                     const float* __restrict__ gates,// [NTOK][E]
                                                     float* __restrict__ outacc) {   // [NTOK][H]
    __shared__ float As[BKK][BM + 4];
    __shared__ float Bs[BKK][BN + 4];
    int t = threadIdx.x;
    int tx = t & 15, ty = t >> 4;
    int row0 = blockIdx.x * BM;
    int col0 = blockIdx.y * BN;
    float facc[4][4] = {};
    for (int e = 0; e < Ee; ++e) {
        const float* A = h2 + (size_t)e * NTOK * Hh;
        const float* Bw = w3 + (size_t)e * Hh * Hh;
        float acc[4][4] = {};
        for (int kb = 0; kb < Hh; kb += BKK) {
            #pragma unroll
            for (int i = 0; i < 8; ++i) {
                int idx = t + i * 256;
                int kk = idx & 31, m = idx >> 5;
                As[kk][m] = A[(size_t)(row0 + m) * Hh + kb + kk];
            }
            #pragma unroll
            for (int i = 0; i < 8; ++i) {
                int idx = t + i * 256;
                int kk = idx & 31, n = idx >> 5;
                Bs[kk][n] = Bw[(size_t)(col0 + n) * Hh + kb + kk];
            }
            __syncthreads();
            #pragma unroll
            for (int kk = 0; kk < BKK; ++kk) {
                float a[4], bv[4];
                #pragma unroll
                for (int j = 0; j < 4; ++j) a[j] = As[kk][ty * 4 + j];
                #pragma unroll
                for (int j = 0; j < 4; ++j) bv[j] = Bs[kk][tx * 4 + j];
                #pragma unroll
                for (int i = 0; i < 4; ++i)
                    #pragma unroll
                    for (int j = 0; j < 4; ++j) acc[i][j] += a[i] * bv[j];
            }
            __syncthreads();
        }
        #pragma unroll
        for (int i = 0; i < 4; ++i) {
            float g = gates[(size_t)(row0 + ty * 4 + i) * Ee + e];
            #pragma unroll
            for (int j = 0; j < 4; ++j)
                facc[i][j] += g * (acc[i][j] + b3[(size_t)e * Hh + col0 + tx * 4 + j]);
        }
    }
    #pragma unroll
    for (int i = 0; i < 4; ++i)
        #pragma unroll
        for (int j = 0; j < 4; ++j)
            outacc[(size_t)(row0 + ty * 4 + i) * Hh + col0 + tx * 4 + j] = facc[i][j];
}

// -------- final transpose [B][D][H] -> [B][H][D] --------
__global__ __launch_bounds__(256) void transpose_out(const float* __restrict__ outacc, // [B*D][H]
                                                     float* __restrict__ out) {        // [B][H][D]
    __shared__ float tile[32][33];
    int b = blockIdx.z;
    int d0 = blockIdx.x * 32;
    int o0 = blockIdx.y * 32;
    int tx = threadIdx.x & 31, ty = threadIdx.x >> 5;  // 8 rows/pass
    for (int i = 0; i < 32; i += 8)
        tile[ty + i][tx] = outacc[((size_t)b * Dd + d0 + ty + i) * Hh + o0 + tx];
    __syncthreads();
    for (int i = 0; i < 32; i += 8)
        out[((size_t)b * Hh + o0 + ty + i) * Dd + d0 + tx] = tile[tx][ty + i];
}

extern "C" void kernel_launch(void* const* d_in, const int* in_sizes, int n_in,
                              void* d_out, int out_size, void* d_ws, size_t ws_size,
                              hipStream_t stream) {
    const float* x       = (const float*)d_in[0];
    const float* conv_w  = (const float*)d_in[1];
    const float* conv_b  = (const float*)d_in[2];
    const float* fl_w    = (const float*)d_in[3];
    const float* fl_b    = (const float*)d_in[4];
    const float* w1      = (const float*)d_in[5];
    const float* b1      = (const float*)d_in[6];
    const float* w2      = (const float*)d_in[7];
    const float* b2      = (const float*)d_in[8];
    const float* w3      = (const float*)d_in[9];
    const float* b3      = (const float*)d_in[10];
    float* out = (float*)d_out;

    char* ws = (char*)d_ws;
    // Layout (bytes):
    //   h1     @ 0          : 8*2048*1024*4 = 67108864
    //   xe     @ 67108864   : 8*2048*512*4  = 33554432   (dead after GEMM1)
    //   h2     @ 67108864   : 67108864                   (overlays xe — legal, stream-ordered)
    //   c0     @ 134217728  : 8388608
    //   c1     @ 142606336  : 8388608                    (reused as outacc after convs)
    //   wr     @ 150994944  : 2359296
    //   logits @ 153354240  : 65536
    //   gates  @ 153419776  : 65536
    float* h1     = (float*)(ws);
    float* xe     = (float*)(ws + 67108864);
    float* h2     = (float*)(ws + 67108864);
    float* c0     = (float*)(ws + 134217728);
    float* c1     = (float*)(ws + 142606336);
    float* wr     = (float*)(ws + 150994944);
    float* logits = (float*)(ws + 153354240);
    float* gates  = (float*)(ws + 153419776);
    float* outacc = c1;

    hipMemsetAsync(logits, 0, NTOK * Ee * sizeof(float), stream);
    repack_conv_w<<<2304, 256, 0, stream>>>(conv_w, wr);

    // Router convs (fp32 — discrete top-k downstream, keep exact)
    conv_gemm<<<dim3(Bb * Ll / BM, Dd / BN), 256, 0, stream>>>(x,  wr + 0 * 3 * Dd * Dd, conv_b + 0 * Dd, c0, 1);
    conv_gemm<<<dim3(Bb * Ll / BM, Dd / BN), 256, 0, stream>>>(c0, wr + 1 * 3 * Dd * Dd, conv_b + 1 * Dd, c1, 2);
    conv_gemm<<<dim3(Bb * Ll / BM, Dd / BN), 256, 0, stream>>>(c1, wr + 2 * 3 * Dd * Dd, conv_b + 2 * Dd, c0, 4);

    logits_accum<<<dim3(Bb, 8), 256, 0, stream>>>(c0, fl_w, logits);
    gates_final<<<NTOK / 256, 256, 0, stream>>>(logits, fl_b, gates);

    downsample<<<dim3(NTOK, Ee), 256, 0, stream>>>(x, xe);

    // Expert MLP
    gemm_nt<<<dim3(NTOK / BM, Hh / BN, Ee), 256, 0, stream>>>(xe, w1, b1, h1, NTOK, Hh, LMAXc, 1);
    gemm_nt<<<dim3(NTOK / BM, Hh / BN, Ee), 256, 0, stream>>>(h1, w2, b2, h2, NTOK, Hh, Hh, 1);
    gemm3_combine<<<dim3(NTOK / BM, Hh / BN), 256, 0, stream>>>(h2, w3, b3, gates, outacc);

    transpose_out<<<dim3(Dd / 32, Hh / 32, Bb), 256, 0, stream>>>(outacc, out);
}

// Round 2
// 806.844 us; speedup vs baseline: 2.1580x; 2.1580x over previous
//
#include <hip/hip_runtime.h>
#include <math.h>

#define Bb 8
#define Ll 1024
#define Dd 256
#define Ee 8
#define Hh 1024
#define LMAXc 512
#define NTOK (Bb*Dd)   // 2048

// fp32 conv path tiles
#define BM 64
#define BN 64
#define BKK 32

typedef short bf16x8 __attribute__((ext_vector_type(8)));
typedef float f32x4 __attribute__((ext_vector_type(4)));

__device__ __forceinline__ float gelu_f(float x) {
    return 0.5f * x * (1.0f + erff(x * 0.70710678118654752440f));
}

__device__ __forceinline__ unsigned short f2b(float x) {          // RTN fp32->bf16
    unsigned int u = __float_as_uint(x);
    return (unsigned short)((u + 0x7fffu + ((u >> 16) & 1u)) >> 16);
}
__device__ __forceinline__ float b2f(unsigned short h) {
    return __uint_as_float(((unsigned int)h) << 16);
}

__device__ __forceinline__ void gl_lds16(const void* g, void* l) {
    __builtin_amdgcn_global_load_lds((const __attribute__((address_space(1))) unsigned int*)g,
                                     (__attribute__((address_space(3))) unsigned int*)l, 16, 0, 0);
}

// ============================================================================
// Split-bf16 MFMA GEMM (NT): C = A @ B^T, A pre-split bf16 hi/lo planes,
// B fp32 converted hi/lo on the fly during LDS staging.
// 128x128 tile, 4 waves (2x2 of 64x64), 16x16x32 bf16 MFMA, BK=32.
// LDS chunk swizzle: slot(r,q) = r*4 + (q ^ ((r>>1)&3))  -> 2-way max conflicts.
// MODE 0: C = gelu(acc+bias) stored as hi/lo bf16 planes.
// MODE 1: atomicAdd(outf[r][c], g[r][e]*(acc+bias[c])), skip g==0 rows.
// ============================================================================
template<int MODE>
__global__ __launch_bounds__(256, 2) void gemm_split(
    const unsigned short* __restrict__ AhiG, const unsigned short* __restrict__ AloG,
    const float* __restrict__ BwG, const float* __restrict__ biasG,
    const float* __restrict__ gates,
    unsigned short* __restrict__ Chi, unsigned short* __restrict__ Clo,
    float* __restrict__ outf,
    int M, int N, int K)
{
    __shared__ char smem[32768];   // Ahi 8K | Alo 8K | Bhi 8K | Blo 8K
    char* sAhi = smem;
    char* sAlo = smem + 8192;
    char* sBhi = smem + 16384;
    char* sBlo = smem + 24576;

    const int e = blockIdx.z;
    const unsigned short* Ahi = AhiG + (size_t)e * M * K;
    const unsigned short* Alo = AloG + (size_t)e * M * K;
    const float* Bw  = BwG  + (size_t)e * N * K;
    const float* bias = biasG + (size_t)e * N;

    const int t = threadIdx.x;
    const int lane = t & 63, w = t >> 6;
    const int r16 = lane & 15, quad = lane >> 4;
    const int wr = w >> 1, wc = w & 1;
    const int row0 = blockIdx.x * 128, col0 = blockIdx.y * 128;

    // fragment LDS byte offsets (constant across k-steps)
    int aoff[4], boff[4];
    #pragma unroll
    for (int i = 0; i < 4; ++i) {
        int ra = wr * 64 + i * 16 + r16;
        aoff[i] = ra * 64 + ((quad ^ ((ra >> 1) & 3)) << 4);
        int rb = wc * 64 + i * 16 + r16;
        boff[i] = rb * 64 + ((quad ^ ((rb >> 1) & 3)) << 4);
    }

    // staging slots: thread t handles slots t and t+256 (512 slots x 16B per plane)
    const int s0 = t, s1 = t + 256;
    const int r0s = s0 >> 2, c0s = ((s0 & 3) ^ ((r0s >> 1) & 3)) << 3;  // elem offset
    const int r1s = s1 >> 2, c1s = ((s1 & 3) ^ ((r1s >> 1) & 3)) << 3;
    const unsigned short* gAhi0 = Ahi + (size_t)(row0 + r0s) * K + c0s;
    const unsigned short* gAhi1 = Ahi + (size_t)(row0 + r1s) * K + c1s;
    const unsigned short* gAlo0 = Alo + (size_t)(row0 + r0s) * K + c0s;
    const unsigned short* gAlo1 = Alo + (size_t)(row0 + r1s) * K + c1s;
    const float* gB0 = Bw + (size_t)(col0 + r0s) * K + c0s;
    const float* gB1 = Bw + (size_t)(col0 + r1s) * K + c1s;

    f32x4 acc[4][4];
    const f32x4 zero4 = {0.f, 0.f, 0.f, 0.f};
    #pragma unroll
    for (int i = 0; i < 4; ++i)
        #pragma unroll
        for (int j = 0; j < 4; ++j) acc[i][j] = zero4;

    for (int k0 = 0; k0 < K; k0 += 32) {
        // A planes: async global->LDS (wave-uniform base + lane*16)
        gl_lds16(gAhi0 + k0, sAhi + (w << 10));
        gl_lds16(gAhi1 + k0, sAhi + 4096 + (w << 10));
        gl_lds16(gAlo0 + k0, sAlo + (w << 10));
        gl_lds16(gAlo1 + k0, sAlo + 4096 + (w << 10));
        // B plane: fp32 load -> hi/lo split -> ds_write_b128
        {
            float v[8];
            *(float4*)&v[0] = *(const float4*)(gB0 + k0);
            *(float4*)&v[4] = *(const float4*)(gB0 + k0 + 4);
            bf16x8 hi, lo;
            #pragma unroll
            for (int i = 0; i < 8; ++i) {
                unsigned short h = f2b(v[i]);
                hi[i] = (short)h; lo[i] = (short)f2b(v[i] - b2f(h));
            }
            *(bf16x8*)(sBhi + s0 * 16) = hi;
            *(bf16x8*)(sBlo + s0 * 16) = lo;
            *(float4*)&v[0] = *(const float4*)(gB1 + k0);
            *(float4*)&v[4] = *(const float4*)(gB1 + k0 + 4);
            #pragma unroll
            for (int i = 0; i < 8; ++i) {
                unsigned short h = f2b(v[i]);
                hi[i] = (short)h; lo[i] = (short)f2b(v[i] - b2f(h));
            }
            *(bf16x8*)(sBhi + s1 * 16) = hi;
            *(bf16x8*)(sBlo + s1 * 16) = lo;
        }
        __syncthreads();
        bf16x8 ah[4], al[4], bh[4], bl[4];
        #pragma unroll
        for (int i = 0; i < 4; ++i) {
            ah[i] = *(const bf16x8*)(sAhi + aoff[i]);
            al[i] = *(const bf16x8*)(sAlo + aoff[i]);
            bh[i] = *(const bf16x8*)(sBhi + boff[i]);
            bl[i] = *(const bf16x8*)(sBlo + boff[i]);
        }
        #pragma unroll
        for (int mi = 0; mi < 4; ++mi)
            #pragma unroll
            for (int ni = 0; ni < 4; ++ni) {
                acc[mi][ni] = __builtin_amdgcn_mfma_f32_16x16x32_bf16(ah[mi], bh[ni], acc[mi][ni], 0, 0, 0);
                acc[mi][ni] = __builtin_amdgcn_mfma_f32_16x16x32_bf16(ah[mi], bl[ni], acc[mi][ni], 0, 0, 0);
                acc[mi][ni] = __builtin_amdgcn_mfma_f32_16x16x32_bf16(al[mi], bh[ni], acc[mi][ni], 0, 0, 0);
            }
        __syncthreads();
    }

    int cc[4]; float bv[4];
    #pragma unroll
    for (int ni = 0; ni < 4; ++ni) {
        cc[ni] = col0 + wc * 64 + ni * 16 + r16;
        bv[ni] = bias[cc[ni]];
    }
    if (MODE == 0) {
        unsigned short* ChiE = Chi + (size_t)e * M * N;
        unsigned short* CloE = Clo + (size_t)e * M * N;
        #pragma unroll
        for (int mi = 0; mi < 4; ++mi) {
            int rb = row0 + wr * 64 + mi * 16 + quad * 4;
            #pragma unroll
            for (int reg = 0; reg < 4; ++reg) {
                size_t roff = (size_t)(rb + reg) * N;
                #pragma unroll
                for (int ni = 0; ni < 4; ++ni) {
                    float vv = gelu_f(acc[mi][ni][reg] + bv[ni]);
                    unsigned short h = f2b(vv);
                    ChiE[roff + cc[ni]] = h;
                    CloE[roff + cc[ni]] = f2b(vv - b2f(h));
                }
            }
        }
    } else {
        #pragma unroll
        for (int mi = 0; mi < 4; ++mi) {
            int rb = row0 + wr * 64 + mi * 16 + quad * 4;
            #pragma unroll
            for (int reg = 0; reg < 4; ++reg) {
                float g = gates[(size_t)(rb + reg) * Ee + e];
                if (g != 0.0f) {
                    size_t roff = (size_t)(rb + reg) * N;
                    #pragma unroll
                    for (int ni = 0; ni < 4; ++ni)
                        atomicAdd(&outf[roff + cc[ni]], g * (acc[mi][ni][reg] + bv[ni]));
                }
            }
        }
    }
}

// ============================ fp32 router path ==============================

__global__ __launch_bounds__(256) void repack_conv_w(const float* __restrict__ cw,
                                                     float* __restrict__ wrp) {
    int idx = blockIdx.x * 256 + threadIdx.x;      // 3*3*256*256 = 589824 exact
    int i = idx & (Dd - 1);
    int o = (idx >> 8) & (Dd - 1);
    int lk = idx >> 16;
    int layer = lk / 3;
    int k = lk % 3;
    wrp[idx] = cw[(((size_t)layer * Dd + o) * Dd + i) * 3 + k];
}

__global__ __launch_bounds__(256) void conv_gemm(const float* __restrict__ in,
                                                 const float* __restrict__ wrL,
                                                 const float* __restrict__ bias,
                                                 float* __restrict__ out,
                                                 int dil) {
    __shared__ float As[BKK][BM + 4];
    __shared__ float Bs[BKK][BN + 4];
    int t = threadIdx.x;
    int tx = t & 15, ty = t >> 4;
    int row0 = blockIdx.x * BM;
    int b = row0 / Ll;
    int l0 = row0 % Ll;
    int col0 = blockIdx.y * BN;
    float acc[4][4] = {};
    for (int k = 0; k < 3; ++k) {
        int sh = (k - 1) * dil;
        const float* wk = wrL + (size_t)k * Dd * Dd;
        for (int kb = 0; kb < Dd; kb += BKK) {
            #pragma unroll
            for (int i = 0; i < 8; ++i) {
                int idx = t + i * 256;
                int kk = idx & 31, m = idx >> 5;
                int l = l0 + m + sh;
                As[kk][m] = (l >= 0 && l < Ll) ? in[((size_t)b * Ll + l) * Dd + kb + kk] : 0.0f;
            }
            #pragma unroll
            for (int i = 0; i < 8; ++i) {
                int idx = t + i * 256;
                int kk = idx & 31, n = idx >> 5;
                Bs[kk][n] = wk[(size_t)(col0 + n) * Dd + kb + kk];
            }
            __syncthreads();
            #pragma unroll
            for (int kk = 0; kk < BKK; ++kk) {
                float a[4], bvv[4];
                #pragma unroll
                for (int j = 0; j < 4; ++j) a[j] = As[kk][ty * 4 + j];
                #pragma unroll
                for (int j = 0; j < 4; ++j) bvv[j] = Bs[kk][tx * 4 + j];
                #pragma unroll
                for (int i = 0; i < 4; ++i)
                    #pragma unroll
                    for (int j = 0; j < 4; ++j) acc[i][j] += a[i] * bvv[j];
            }
            __syncthreads();
        }
    }
    #pragma unroll
    for (int i = 0; i < 4; ++i) {
        int l = l0 + ty * 4 + i;
        #pragma unroll
        for (int j = 0; j < 4; ++j) {
            int o = col0 + tx * 4 + j;
            out[((size_t)b * Ll + l) * Dd + o] = gelu_f(acc[i][j] + bias[o]);
        }
    }
}

__global__ __launch_bounds__(256) void logits_accum(const float* __restrict__ h,
                                                    const float* __restrict__ fl_w,
                                                    float* __restrict__ logits) {
    int b = blockIdx.x;
    int chunk = blockIdx.y;
    __shared__ float wsm[Ee][128];
    for (int i = threadIdx.x; i < Ee * 128; i += 256) {
        int e = i >> 7, l = i & 127;
        wsm[e][l] = fl_w[e * Ll + chunk * 128 + l];
    }
    __syncthreads();
    int d = threadIdx.x;
    float acc[Ee] = {};
    for (int l = 0; l < 128; ++l) {
        float v = h[((size_t)b * Ll + chunk * 128 + l) * Dd + d];
        #pragma unroll
        for (int e = 0; e < Ee; ++e) acc[e] += v * wsm[e][l];
    }
    int tok = b * Dd + d;
    #pragma unroll
    for (int e = 0; e < Ee; ++e) atomicAdd(&logits[tok * Ee + e], acc[e]);
}

__global__ __launch_bounds__(256) void gates_final(const float* __restrict__ logits,
                                                   const float* __restrict__ fl_b,
                                                   float* __restrict__ gates) {
    int tok = blockIdx.x * 256 + threadIdx.x;
    if (tok >= NTOK) return;
    float s[Ee];
    #pragma unroll
    for (int e = 0; e < Ee; ++e) {
        float z = logits[tok * Ee + e] + fl_b[e];
        s[e] = 1.0f / (1.0f + expf(-z));
    }
    float mx = s[0];
    #pragma unroll
    for (int e = 1; e < Ee; ++e) mx = fmaxf(mx, s[e]);
    float p[Ee];
    #pragma unroll
    for (int e = 0; e < Ee; ++e) p[e] = expf(s[e] - mx);
    int i1 = 0;
    #pragma unroll
    for (int e = 1; e < Ee; ++e) if (p[e] > p[i1]) i1 = e;
    int i2 = (i1 == 0) ? 1 : 0;
    #pragma unroll
    for (int e = 0; e < Ee; ++e) {
        if (e == i1 || e == i2) continue;
        if (p[e] > p[i2]) i2 = e;
    }
    float inv = 1.0f / (p[i1] + p[i2]);
    #pragma unroll
    for (int e = 0; e < Ee; ++e) gates[tok * Ee + e] = 0.0f;
    gates[tok * Ee + i1] = p[i1] * inv;
    gates[tok * Ee + i2] = p[i2] * inv;
}

// per-expert avg-pool downsample -> hi/lo bf16 planes, zero-padded to LMAX
__global__ __launch_bounds__(256) void downsample_split(const float* __restrict__ x,
                                                        unsigned short* __restrict__ xehi,
                                                        unsigned short* __restrict__ xelo) {
    int e = blockIdx.y;
    int tok = blockIdx.x;
    int b = tok >> 8, d = tok & 255;
    int f = e + 2;
    int Li = Ll / f;
    float invf = 1.0f / (float)f;
    for (int j = threadIdx.x; j < LMAXc; j += 256) {
        unsigned short h = 0, l = 0;
        if (j < Li) {
            float v = 0.0f;
            for (int r = 0; r < f; ++r) v += x[((size_t)b * Ll + j * f + r) * Dd + d];
            v *= invf;
            h = f2b(v);
            l = f2b(v - b2f(h));
        }
        size_t idx = ((size_t)e * NTOK + tok) * LMAXc + j;
        xehi[idx] = h;
        xelo[idx] = l;
    }
}

__global__ __launch_bounds__(256) void transpose_out(const float* __restrict__ outacc,
                                                     float* __restrict__ out) {
    __shared__ float tile[32][33];
    int b = blockIdx.z;
    int d0 = blockIdx.x * 32;
    int o0 = blockIdx.y * 32;
    int tx = threadIdx.x & 31, ty = threadIdx.x >> 5;
    for (int i = 0; i < 32; i += 8)
        tile[ty + i][tx] = outacc[((size_t)b * Dd + d0 + ty + i) * Hh + o0 + tx];
    __syncthreads();
    for (int i = 0; i < 32; i += 8)
        out[((size_t)b * Hh + o0 + ty + i) * Dd + d0 + tx] = tile[tx][ty + i];
}

extern "C" void kernel_launch(void* const* d_in, const int* in_sizes, int n_in,
                              void* d_out, int out_size, void* d_ws, size_t ws_size,
                              hipStream_t stream) {
    const float* x       = (const float*)d_in[0];
    const float* conv_w  = (const float*)d_in[1];
    const float* conv_b  = (const float*)d_in[2];
    const float* fl_w    = (const float*)d_in[3];
    const float* fl_b    = (const float*)d_in[4];
    const float* w1      = (const float*)d_in[5];
    const float* b1      = (const float*)d_in[6];
    const float* w2      = (const float*)d_in[7];
    const float* b2      = (const float*)d_in[8];
    const float* w3      = (const float*)d_in[9];
    const float* b3      = (const float*)d_in[10];
    float* out = (float*)d_out;

    char* ws = (char*)d_ws;
    // Workspace layout (total 142,737,408 B — under the 153.5 MB proven in R1):
    //   h1hi  @ 0            33,554,432   [E][NTOK][H] bf16
    //   h1lo  @ 33,554,432   33,554,432
    //   xehi  @ 67,108,864   16,777,216   -> h2hi (33,554,432) after GEMM1 (xe dead)
    //   xelo  @ 83,886,080   16,777,216
    //   C     @ 100,663,296  33,554,432 : c0 (8.39M) + wr (2.36M) -> h2lo after router
    //   c1    @ 134,217,728   8,388,608   conv buf, reused as outacc
    //   logits@ 142,606,336      65,536
    //   gates @ 142,671,872      65,536
    unsigned short* h1hi = (unsigned short*)(ws);
    unsigned short* h1lo = (unsigned short*)(ws + 33554432);
    unsigned short* xehi = (unsigned short*)(ws + 67108864);
    unsigned short* xelo = (unsigned short*)(ws + 83886080);
    unsigned short* h2hi = (unsigned short*)(ws + 67108864);
    unsigned short* h2lo = (unsigned short*)(ws + 100663296);
    float* c0     = (float*)(ws + 100663296);
    float* wrp    = (float*)(ws + 109051904);
    float* c1     = (float*)(ws + 134217728);
    float* logits = (float*)(ws + 142606336);
    float* gates  = (float*)(ws + 142671872);
    float* outacc = c1;

    hipMemsetAsync(logits, 0, NTOK * Ee * sizeof(float), stream);
    repack_conv_w<<<2304, 256, 0, stream>>>(conv_w, wrp);

    // Router convs (fp32 — feeds discrete top-k, keep exact)
    conv_gemm<<<dim3(Bb * Ll / BM, Dd / BN), 256, 0, stream>>>(x,  wrp + 0 * 3 * Dd * Dd, conv_b + 0 * Dd, c0, 1);
    conv_gemm<<<dim3(Bb * Ll / BM, Dd / BN), 256, 0, stream>>>(c0, wrp + 1 * 3 * Dd * Dd, conv_b + 1 * Dd, c1, 2);
    conv_gemm<<<dim3(Bb * Ll / BM, Dd / BN), 256, 0, stream>>>(c1, wrp + 2 * 3 * Dd * Dd, conv_b + 2 * Dd, c0, 4);

    logits_accum<<<dim3(Bb, 8), 256, 0, stream>>>(c0, fl_w, logits);
    gates_final<<<NTOK / 256, 256, 0, stream>>>(logits, fl_b, gates);

    downsample_split<<<dim3(NTOK, Ee), 256, 0, stream>>>(x, xehi, xelo);

    // zero the atomic accumulator (outacc aliases c1, convs are done with it before GEMM3)
    hipMemsetAsync(outacc, 0, (size_t)NTOK * Hh * sizeof(float), stream);

    // Expert MLP: split-bf16 MFMA
    gemm_split<0><<<dim3(NTOK / 128, Hh / 128, Ee), 256, 0, stream>>>(
        xehi, xelo, w1, b1, nullptr, h1hi, h1lo, nullptr, NTOK, Hh, LMAXc);
    gemm_split<0><<<dim3(NTOK / 128, Hh / 128, Ee), 256, 0, stream>>>(
        h1hi, h1lo, w2, b2, nullptr, h2hi, h2lo, nullptr, NTOK, Hh, Hh);
    gemm_split<1><<<dim3(NTOK / 128, Hh / 128, Ee), 256, 0, stream>>>(
        h2hi, h2lo, w3, b3, gates, nullptr, nullptr, outacc, NTOK, Hh, Hh);

    transpose_out<<<dim3(Dd / 32, Hh / 32, Bb), 256, 0, stream>>>(outacc, out);
}